// Round 1
// baseline (677.292 us; speedup 1.0000x reference)
//
#include <hip/hip_runtime.h>
#include <hip/hip_bf16.h>

// LGA3D2: out = A_g(A_g(x)) where A_g is local guided aggregation
// x: [B,C,D,H,W] fp32, g: [B,75,H,W] fp32, out: [B,C,D,H,W] fp32
// A_g: out[b,c,d,h,w] = sum_{i,j in 5x5, k in 0..2}
//        g[b,(i*5+j)*3+k,h,w] * x[b,c,d+k-1,h+i-2,w+j-2]   (zero padded)

constexpr int RAD = 2;
constexpr int BB = 2, CC = 16, DD = 48, HH = 128, WW = 256;
constexpr int GG = 75;            // 3 * 5 * 5
constexpr int DCHUNK = 16;
constexpr int NDC = DD / DCHUNK;  // 3

__device__ __forceinline__ float ldv(const float* p) { return *p; }
__device__ __forceinline__ float ldv(const __hip_bfloat16* p) { return __bfloat162float(*p); }
__device__ __forceinline__ void stv(float* p, float v) { *p = v; }
__device__ __forceinline__ void stv(__hip_bfloat16* p, float v) { *p = __float2bfloat16(v); }

// One aggregation pass. Block = (b, c, h, d-chunk); 256 threads span W.
// Each thread accumulates DCHUNK depth outputs in registers (scatter form:
// each x load feeds 3 FMAs into acc[a-1], acc[a], acc[a+1]).
template <typename IT, typename OT>
__global__ __launch_bounds__(WW) void lga_pass(const IT* __restrict__ x,
                                               const float* __restrict__ g,
                                               OT* __restrict__ out) {
  const int bid = blockIdx.x;
  const int d0 = (bid % NDC) * DCHUNK;
  const int h  = (bid / NDC) % HH;
  const int c  = (bid / (NDC * HH)) % CC;
  const int b  =  bid / (NDC * HH * CC);
  const int w  = threadIdx.x;

  const size_t plane = (size_t)HH * WW;

  float acc[DCHUNK];
#pragma unroll
  for (int a = 0; a < DCHUNK; ++a) acc[a] = 0.f;

  const IT* xb = x + ((size_t)(b * CC + c)) * DD * plane;
  const float* gp = g + (size_t)b * GG * plane + (size_t)h * WW + w;

  for (int i = 0; i < 5; ++i) {
    const int hr = h + i - RAD;
    if (hr < 0 || hr >= HH) continue;  // uniform per block (h is block-uniform)
    for (int j = 0; j < 5; ++j) {
      const int wr = w + j - RAD;
      const bool wok = (wr >= 0) && (wr < WW);
      const int gi = (i * 5 + j) * 3;
      // guidance weights indexed at OUTPUT coords (h,w); coalesced across lanes
      const float g0 = gp[(size_t)(gi + 0) * plane];
      const float g1 = gp[(size_t)(gi + 1) * plane];
      const float g2 = gp[(size_t)(gi + 2) * plane];
      const IT* xcol = xb + (size_t)d0 * plane + (size_t)hr * WW + wr;
#pragma unroll
      for (int a = -1; a <= DCHUNK; ++a) {
        bool dok = true;
        if (a == -1) dok = (d0 > 0);                 // depth zero-pad low
        if (a == DCHUNK) dok = (d0 + DCHUNK < DD);   // depth zero-pad high
        const float xv = (wok && dok)
                             ? ldv(xcol + (ptrdiff_t)a * (ptrdiff_t)plane)
                             : 0.f;
        // x at depth d0+a contributes:
        //   out[d0+a+1] with weight k=0, out[d0+a] with k=1, out[d0+a-1] with k=2
        if (a + 1 < DCHUNK) acc[a + 1] += g0 * xv;   // a+1 >= 0 always
        if (a >= 0 && a < DCHUNK) acc[a] += g1 * xv;
        if (a >= 1) acc[a - 1] += g2 * xv;           // a-1 < DCHUNK always
      }
    }
  }

  OT* ob = out + (((size_t)(b * CC + c) * DD) + d0) * plane + (size_t)h * WW + w;
#pragma unroll
  for (int a = 0; a < DCHUNK; ++a) stv(ob + (size_t)a * plane, acc[a]);
}

extern "C" void kernel_launch(void* const* d_in, const int* in_sizes, int n_in,
                              void* d_out, int out_size, void* d_ws, size_t ws_size,
                              hipStream_t stream) {
  const float* x = (const float*)d_in[0];
  const float* g = (const float*)d_in[1];
  float* out = (float*)d_out;

  const size_t elems = (size_t)BB * CC * DD * HH * WW;
  const dim3 grid(BB * CC * HH * NDC);
  const dim3 block(WW);

  if (ws_size >= elems * sizeof(float)) {
    // fp32 intermediate in workspace
    float* y = (float*)d_ws;
    lga_pass<float, float><<<grid, block, 0, stream>>>(x, g, y);
    lga_pass<float, float><<<grid, block, 0, stream>>>(y, g, out);
  } else {
    // bf16 intermediate (half the workspace); error ~1e-2 << 9.75e-2 threshold
    __hip_bfloat16* y = (__hip_bfloat16*)d_ws;
    lga_pass<float, __hip_bfloat16><<<grid, block, 0, stream>>>(x, g, y);
    lga_pass<__hip_bfloat16, float><<<grid, block, 0, stream>>>(y, g, out);
  }
}